// Round 3
// baseline (410.895 us; speedup 1.0000x reference)
//
#include <hip/hip_runtime.h>
#include <stdint.h>

typedef int   int4v __attribute__((ext_vector_type(4)));
typedef float f32x4 __attribute__((ext_vector_type(4)));

// ---- workspace layout (bytes) ----
#define WS_SCALES 0ull
#define WS_ZERO   256ull
#define WS_BI1    1024ull
#define WS_BI2    2048ull
#define WS_BI3    4096ull
#define WS_BIS    8192ull
#define WS_W1Q    16384ull                     // int8 [256][512]
#define WS_W2Q    (WS_W1Q + 131072ull)         // int8 [256][2304]  k=(kh*3+kw)*256+c
#define WS_W3Q    (WS_W2Q + 589824ull)         // int8 [1024][256]
#define WS_WSQ    (WS_W3Q + 262144ull)         // int8 [1024][512]
#define WS_A0     2097152ull                   // int8 [50176][512]  (= [64][784][512])
#define WS_A1     (WS_A0 + 25690112ull)        // int8 [50176][256]
#define WS_A2     (WS_A1 + 12845056ull)        // int8 [12544][256]  (= [64][196][256])

__global__ void k_init(float* wshead) {
    int i = blockIdx.x * 256 + threadIdx.x;
    wshead[i] = 0.0f;   // 16 blocks x 256 = 16 KB: scales+zero page+biases
}

__global__ void k_maxabs(const float* __restrict__ w1, const float* __restrict__ w2,
                         const float* __restrict__ w3, const float* __restrict__ wsd,
                         float* __restrict__ scales) {
    const float* srcs[4] = {w1, w2, w3, wsd};
    const int ns[4] = {131072, 589824, 262144, 524288};
    int t = blockIdx.y;
    const float* s = srcs[t];
    int n = ns[t];
    float m = 0.0f;
    for (int i = blockIdx.x * 256 + threadIdx.x; i < n; i += gridDim.x * 256)
        m = fmaxf(m, fabsf(s[i]));
    __shared__ float red[256];
    red[threadIdx.x] = m;
    __syncthreads();
    for (int st = 128; st > 0; st >>= 1) {
        if (threadIdx.x < st) red[threadIdx.x] = fmaxf(red[threadIdx.x], red[threadIdx.x + st]);
        __syncthreads();
    }
    if (threadIdx.x == 0) atomicMax((int*)&scales[t], __float_as_int(red[0]));
}

__global__ void k_quant_w(const float* __restrict__ w1, const float* __restrict__ w2,
                          const float* __restrict__ w3, const float* __restrict__ wsd,
                          const float* __restrict__ b1, const float* __restrict__ b2,
                          const float* __restrict__ b3, const float* __restrict__ bs,
                          char* __restrict__ wsb) {
    const float* sc = (const float*)(wsb + WS_SCALES);
    int mode = blockIdx.y;
    int i0 = blockIdx.x * 256 + threadIdx.x;
    int stride = gridDim.x * 256;
    if (mode == 0) {
        float s = sc[0]; signed char* o = (signed char*)(wsb + WS_W1Q);
        for (int i = i0; i < 131072; i += stride)
            o[i] = (signed char)(int)rintf(fminf(fmaxf(w1[i] / s, -1.f), 1.f) * 127.f);
    } else if (mode == 1) {
        float s = sc[1]; signed char* o = (signed char*)(wsb + WS_W2Q);
        for (int i = i0; i < 589824; i += stride) {
            int oo = i / 2304, r2 = i - oo * 2304;
            int c = r2 / 9, kk = r2 - c * 9;
            o[(size_t)oo * 2304 + kk * 256 + c] =
                (signed char)(int)rintf(fminf(fmaxf(w2[i] / s, -1.f), 1.f) * 127.f);
        }
    } else if (mode == 2) {
        float s = sc[2]; signed char* o = (signed char*)(wsb + WS_W3Q);
        for (int i = i0; i < 262144; i += stride)
            o[i] = (signed char)(int)rintf(fminf(fmaxf(w3[i] / s, -1.f), 1.f) * 127.f);
    } else if (mode == 3) {
        float s = sc[3]; signed char* o = (signed char*)(wsb + WS_WSQ);
        for (int i = i0; i < 524288; i += stride)
            o[i] = (signed char)(int)rintf(fminf(fmaxf(wsd[i] / s, -1.f), 1.f) * 127.f);
    } else if (mode == 4) {
        float* o = (float*)(wsb + WS_BI1);
        for (int i = i0; i < 256; i += stride) o[i] = rintf(b1[i] * 127.f);
    } else if (mode == 5) {
        float* o = (float*)(wsb + WS_BI2);
        for (int i = i0; i < 256; i += stride) o[i] = rintf(b2[i] * 127.f);
    } else if (mode == 6) {
        float* o = (float*)(wsb + WS_BI3);
        for (int i = i0; i < 1024; i += stride) o[i] = rintf(b3[i] * 127.f);
    } else {
        float* o = (float*)(wsb + WS_BIS);
        for (int i = i0; i < 1024; i += stride) o[i] = rintf(bs[i] * 127.f);
    }
}

// quantize + transpose x: float [64][512][784] -> int8 a0 [64*784][512]
__global__ void k_quant_x(const float* __restrict__ x, signed char* __restrict__ a0) {
    __shared__ signed char tile[32][33];
    int b = blockIdx.z;
    int p0 = blockIdx.x * 32, c0 = blockIdx.y * 32;
    int tp = threadIdx.x & 31, tr = threadIdx.x >> 5;
    const float* xb = x + ((size_t)b * 512 + c0) * 784 + p0;
    for (int i = 0; i < 4; i++) {
        int cc = tr + i * 8;
        float v = (p0 + tp < 784) ? xb[(size_t)cc * 784 + tp] : 0.f;
        v = fminf(fmaxf(v * 2.f, -1.f), 1.f);
        tile[cc][tp] = (signed char)(int)rintf(v * 127.f);
    }
    __syncthreads();
    // out: 4 consecutive c per thread -> 4B stores, 32B contiguous per 8 lanes
    int pp = threadIdx.x >> 3, cs = (threadIdx.x & 7) * 4;
    if (p0 + pp < 784) {
        unsigned pk = 0;
        for (int i = 0; i < 4; i++)
            pk |= (unsigned)(unsigned char)tile[cs + i][pp] << (8 * i);
        *(unsigned*)(a0 + ((size_t)b * 784 + p0 + pp) * 512 + c0 + cs) = pk;
    }
}

// ---------- i8-MFMA GEMM kernels (direct-to-register fragments, no LDS staging) ----------
// MODE 0: conv1  M=256 K=512  Nflat=50176 -> a1 int8 [n][256]
// MODE 1: conv2  M=256 K=2304 Nflat=12544 (im2col 3x3/s2/p1 gather) -> a2 int8 [n][256]
// MODE 2: conv3 (t<4: K=256 a2) + shortcut (t>=4: K=512 a0 strided) -> float out NCHW
//
// Fragment for mfma_i32_16x16x64_i8: lane (quad=lane>>4, lrow=lane&15) holds
// 16 i8 at SRC[row = base+lrow][k0 + quad*16] — loaded DIRECTLY from global
// (identical cache-line footprint to the old staged path; L1/L2 dedups the
// 2x cross-wave fragment sharing). K-loop is barrier-free: register
// double-buffer (named cur/next sets -> static indexing, rule #20), compiler
// inserts precise counted vmcnt for register loads. LDS is epilogue-only.
// Input bytes to each MFMA and accumulation order are bit-identical to the
// previous version.
template <int MODE, int BM, int BN, int WGM, int WGN, int MINW>
__global__ __launch_bounds__(256, MINW) void k_conv(char* __restrict__ wsb, float* __restrict__ dout) {
    constexpr int FM = BM / WGM / 16;
    constexpr int FN = BN / WGN / 16;
    constexpr int KTOT = (MODE == 0) ? 512 : (MODE == 1) ? 2304 : 768;
    constexpr int NSTEP = KTOT / 64;
    constexpr int BMP = BM + 16;                     // padded epi stride (int8 modes)
    constexpr int LDSZ = (MODE == 2) ? BM * (BN + 4) * 4 : BN * BMP;

    __shared__ alignas(16) char lds[LDSZ];

    const int tid = threadIdx.x;
    const int wid = tid >> 6;
    const int lane = tid & 63;
    const int n0 = blockIdx.x * BN;
    const int m0 = blockIdx.y * BM;
    const int bb = blockIdx.z;

    const float* sc = (const float*)(wsb + WS_SCALES);
    const int lrow = lane & 15;
    const int quad = lane >> 4;
    const int wm = (wid % WGM) * (BM / WGM);
    const int wn = (wid / WGM) * (BN / WGN);
    const char* zpq = wsb + WS_ZERO + quad * 16;     // zero page ([256,1024) stays 0)

    // ---- per-lane fragment base pointers (k = 0) ----
    const char* aB[FM];
    const char* aB2[FM];          // MODE 2: shortcut weights
    const char* bB[FN];
    const char* bB2[FN];          // MODE 2: shortcut activations
    int oh2[FN], ow2[FN];         // MODE 1: 2*oh-1 / 2*ow-1 per j

#pragma unroll
    for (int i = 0; i < FM; i++) {
        int m = m0 + wm + i * 16 + lrow;
        if constexpr (MODE == 0) {
            aB[i] = wsb + WS_W1Q + (size_t)m * 512 + quad * 16;
        } else if constexpr (MODE == 1) {
            aB[i] = wsb + WS_W2Q + (size_t)m * 2304 + quad * 16;
        } else {
            aB[i]  = wsb + WS_W3Q + (size_t)m * 256 + quad * 16;
            aB2[i] = wsb + WS_WSQ + (size_t)m * 512 + quad * 16;
        }
    }
#pragma unroll
    for (int j = 0; j < FN; j++) {
        int n = n0 + wn + j * 16 + lrow;
        if constexpr (MODE == 0) {
            bB[j] = wsb + WS_A0 + (size_t)n * 512 + quad * 16;
        } else if constexpr (MODE == 1) {
            unsigned b = (unsigned)n / 196u;
            unsigned hw = (unsigned)n - b * 196u;
            int oh = hw / 14, ow = hw - oh * 14;
            bB[j] = wsb + WS_A1 + (size_t)b * 200704 + quad * 16;
            oh2[j] = 2 * oh - 1;
            ow2[j] = 2 * ow - 1;
        } else {
            if (n < 196) {
                int oh = n / 14, ow = n - oh * 14;
                bB[j]  = wsb + WS_A2 + ((size_t)bb * 196 + n) * 256 + quad * 16;
                bB2[j] = wsb + WS_A0 + ((size_t)bb * 784 + oh * 56 + ow * 2) * 512 + quad * 16;
            } else {
                bB[j] = zpq; bB2[j] = zpq;    // reads land in zeroed [256,1024)
            }
        }
    }

    int4v acc3[FM][FN] = {};
    int4v accS[FM][FN] = {};

    auto loadF = [&](int t, int4v (&a)[FM], int4v (&b)[FN]) {
        if constexpr (MODE == 0) {
            const int off = t * 64;
#pragma unroll
            for (int i = 0; i < FM; i++) a[i] = *(const int4v*)(aB[i] + off);
#pragma unroll
            for (int j = 0; j < FN; j++) b[j] = *(const int4v*)(bB[j] + off);
        } else if constexpr (MODE == 1) {
            const int off = t * 64;
#pragma unroll
            for (int i = 0; i < FM; i++) a[i] = *(const int4v*)(aB[i] + off);
            const int tap = t >> 2, c0 = (t & 3) << 6;
            const int kh = tap / 3, kw = tap - 3 * kh;
#pragma unroll
            for (int j = 0; j < FN; j++) {
                int ih = oh2[j] + kh, iw = ow2[j] + kw;
                const char* g = ((unsigned)ih < 28u && (unsigned)iw < 28u)
                                    ? bB[j] + (ih * 28 + iw) * 256 + c0 : zpq;
                b[j] = *(const int4v*)g;
            }
        } else {
            if (t < 4) {
                const int off = t * 64;
#pragma unroll
                for (int i = 0; i < FM; i++) a[i] = *(const int4v*)(aB[i] + off);
#pragma unroll
                for (int j = 0; j < FN; j++) b[j] = *(const int4v*)(bB[j] + off);
            } else {
                const int off = (t - 4) * 64;
#pragma unroll
                for (int i = 0; i < FM; i++) a[i] = *(const int4v*)(aB2[i] + off);
#pragma unroll
                for (int j = 0; j < FN; j++) b[j] = *(const int4v*)(bB2[j] + off);
            }
        }
    };
    auto MF = [&](int4v (&ac)[FM][FN], int4v (&a)[FM], int4v (&b)[FN]) {
#pragma unroll
        for (int i = 0; i < FM; i++)
#pragma unroll
            for (int j = 0; j < FN; j++)
                ac[i][j] = __builtin_amdgcn_mfma_i32_16x16x64_i8(a[i], b[j], ac[i][j], 0, 0, 0);
    };

    // barrier-free K-loop, register double-buffer (NSTEP is even for all modes)
    int4v aC[FM], bC[FN], aN[FM], bN[FN];
    loadF(0, aC, bC);
    for (int t = 0; t < NSTEP; t += 2) {
        loadF(t + 1, aN, bN);
        if (MODE != 2 || t < 4) MF(acc3, aC, bC); else MF(accS, aC, bC);
        if (t + 2 < NSTEP) loadF(t + 2, aC, bC);
        if (MODE != 2 || t + 1 < 4) MF(acc3, aN, bN); else MF(accS, aN, bN);
    }

    // ---------------- epilogue (C/D map: col=lane&15, row=quad*4+reg) ----------------
    if constexpr (MODE == 0 || MODE == 1) {
        const float alpha = sc[MODE] / 16129.0f;
        const float* bi = (const float*)(wsb + (MODE == 0 ? WS_BI1 : WS_BI2));
        signed char* outp = (signed char*)(wsb + (MODE == 0 ? WS_A1 : WS_A2));
#pragma unroll
        for (int i = 0; i < FM; i++) {
            int mloc = wm + i * 16 + quad * 4;      // local m of r=0
            int mb = m0 + mloc;
            float bt[4];
#pragma unroll
            for (int r = 0; r < 4; r++) bt[r] = bi[mb + r] * (2.0f / 127.0f);
#pragma unroll
            for (int j = 0; j < FN; j++) {
                int nloc = wn + j * 16 + lrow;
                unsigned pk = 0;
#pragma unroll
                for (int r = 0; r < 4; r++) {
                    float v = alpha * (float)acc3[i][j][r] + bt[r];
                    int q = (int)rintf(127.0f * fminf(fmaxf(2.0f * v, 0.0f), 1.0f));
                    pk |= (unsigned)(q & 0xFF) << (8 * r);
                }
                *(unsigned*)(lds + nloc * BMP + mloc) = pk;
            }
        }
        __syncthreads();
        // coalesced copy-out: full 64B-line coverage, rows are [n][256] m-contig
        for (int u = tid; u < BN * (BM / 16); u += 256) {
            int row = u / (BM / 16);
            int seg = u % (BM / 16);
            uint4 v = *(const uint4*)(lds + row * BMP + seg * 16);
            *(uint4*)(outp + (size_t)(n0 + row) * 256 + m0 + seg * 16) = v;
        }
    } else {
        // WGM=1: every wave covers all BM=64 rows for its own 32 columns
        const float c2 = sc[1], c3 = sc[2], cS = sc[3];
        const float* bi3 = (const float*)(wsb + WS_BI3);
        const float* bis = (const float*)(wsb + WS_BIS);
        float* ldsF = (float*)lds;
        constexpr int LDN = BN + 4;
        constexpr int SEGS = BN / 16;
#pragma unroll
        for (int i = 0; i < FM; i++) {
            int mloc = i * 16 + quad * 4;
            int mg = m0 + mloc;
            float bt[4];
#pragma unroll
            for (int r = 0; r < 4; r++)
                bt[r] = bi3[mg + r] * (c3 / (127.0f * c2)) + bis[mg + r] * (1.0f / 127.0f);
#pragma unroll
            for (int j = 0; j < FN; j++) {
                int nloc = wn + j * 16 + lrow;
#pragma unroll
                for (int r = 0; r < 4; r++) {
                    float v = (c3 * (float)acc3[i][j][r] + cS * (float)accS[i][j][r])
                                  * (0.5f / 16129.0f) + bt[r];
                    v = v < 0.0f ? 0.0f : (v > 6.0f ? 6.0f : v);  // NaN-propagating
                    ldsF[(mloc + r) * LDN + nloc] = v;
                }
            }
        }
        __syncthreads();
        // copy out BM rows x BN floats (aligned 16B segments along n)
        {
            int rw0 = tid / SEGS, seg = tid % SEGS;
            int nbase = n0 + seg * 16;
            for (int row = rw0; row < BM; row += 256 / SEGS) {
                const float* src = ldsF + row * LDN + seg * 16;
                float* dst = dout + ((size_t)bb * 1024 + m0 + row) * 196 + nbase;
                if (nbase + 16 <= 196) {
                    *(f32x4*)(dst + 0)  = *(const f32x4*)(src + 0);
                    *(f32x4*)(dst + 4)  = *(const f32x4*)(src + 4);
                    *(f32x4*)(dst + 8)  = *(const f32x4*)(src + 8);
                    *(f32x4*)(dst + 12) = *(const f32x4*)(src + 12);
                } else {
                    for (int q = 0; q < 16 && nbase + q < 196; q++) dst[q] = src[q];
                }
            }
        }
    }
}

extern "C" void kernel_launch(void* const* d_in, const int* in_sizes, int n_in,
                              void* d_out, int out_size, void* d_ws, size_t ws_size,
                              hipStream_t stream) {
    const float* x   = (const float*)d_in[0];
    const float* w1  = (const float*)d_in[1];
    const float* b1  = (const float*)d_in[2];
    const float* w2  = (const float*)d_in[3];
    const float* b2  = (const float*)d_in[4];
    const float* w3  = (const float*)d_in[5];
    const float* b3  = (const float*)d_in[6];
    const float* wsd = (const float*)d_in[7];
    const float* bs  = (const float*)d_in[8];
    float* out = (float*)d_out;
    char* wsb = (char*)d_ws;

    k_init<<<16, 256, 0, stream>>>((float*)wsb);
    k_maxabs<<<dim3(32, 4), 256, 0, stream>>>(w1, w2, w3, wsd, (float*)(wsb + WS_SCALES));
    k_quant_w<<<dim3(96, 8), 256, 0, stream>>>(w1, w2, w3, wsd, b1, b2, b3, bs, wsb);
    k_quant_x<<<dim3(25, 16, 64), 256, 0, stream>>>(x, (signed char*)(wsb + WS_A0));
    k_conv<0, 64, 128, 2, 2, 4><<<dim3(392, 4, 1), 256, 0, stream>>>(wsb, out);  // conv1
    k_conv<1, 64, 128, 2, 2, 3><<<dim3(98, 4, 1), 256, 0, stream>>>(wsb, out);   // conv2
    k_conv<2, 64, 128, 1, 4, 3><<<dim3(2, 16, 64), 256, 0, stream>>>(wsb, out);  // conv3+sc
}

// Round 5
// 334.905 us; speedup vs baseline: 1.2269x; 1.2269x over previous
//
#include <hip/hip_runtime.h>
#include <stdint.h>

typedef int   int4v __attribute__((ext_vector_type(4)));
typedef float f32x4 __attribute__((ext_vector_type(4)));

// ---- workspace layout (bytes) ----
#define WS_SCALES 0ull
#define WS_ZERO   256ull
#define WS_BI1    1024ull
#define WS_BI2    2048ull
#define WS_BI3    4096ull
#define WS_BIS    8192ull
#define WS_W1Q    16384ull                     // int8 [256][512]
#define WS_W2Q    (WS_W1Q + 131072ull)         // int8 [256][2304]  k=(kh*3+kw)*256+c
#define WS_W3Q    (WS_W2Q + 589824ull)         // int8 [1024][256]
#define WS_WSQ    (WS_W3Q + 262144ull)         // int8 [1024][512]
#define WS_A0     2097152ull                   // int8 [50176][512]  (= [64][784][512])
#define WS_A1     (WS_A0 + 25690112ull)        // int8 [50176][256]
#define WS_A2     (WS_A1 + 12845056ull)        // int8 [12544][256]  (= [64][196][256])

__device__ __forceinline__ void gll16(const void* g, void* l) {
    // async global -> LDS, 16B/lane, dest = wave-uniform base + lane*16
    __builtin_amdgcn_global_load_lds((const __attribute__((address_space(1))) void*)g,
                                     (__attribute__((address_space(3))) void*)l, 16, 0, 0);
}

// counted-wait + raw barrier: leave n vmem ops in flight across the barrier.
#define VMCNT_BAR(n) asm volatile("s_waitcnt vmcnt(" #n ")\n\ts_barrier" ::: "memory")

__global__ void k_init(float* wshead) {
    int i = blockIdx.x * 256 + threadIdx.x;
    wshead[i] = 0.0f;   // 16 blocks x 256 = 16 KB: scales+zero page+biases
}

__global__ void k_maxabs(const float* __restrict__ w1, const float* __restrict__ w2,
                         const float* __restrict__ w3, const float* __restrict__ wsd,
                         float* __restrict__ scales) {
    const float* srcs[4] = {w1, w2, w3, wsd};
    const int n4s[4] = {32768, 147456, 65536, 131072};   // element counts / 4
    int t = blockIdx.y;
    const f32x4* s = (const f32x4*)srcs[t];
    int n4 = n4s[t];
    float m = 0.0f;
    for (int i = blockIdx.x * 256 + threadIdx.x; i < n4; i += gridDim.x * 256) {
        f32x4 v = s[i];
        m = fmaxf(m, fmaxf(fmaxf(fabsf(v[0]), fabsf(v[1])), fmaxf(fabsf(v[2]), fabsf(v[3]))));
    }
    __shared__ float red[256];
    red[threadIdx.x] = m;
    __syncthreads();
    for (int st = 128; st > 0; st >>= 1) {
        if (threadIdx.x < st) red[threadIdx.x] = fmaxf(red[threadIdx.x], red[threadIdx.x + st]);
        __syncthreads();
    }
    if (threadIdx.x == 0) atomicMax((int*)&scales[t], __float_as_int(red[0]));
}

__global__ void k_quant_w(const float* __restrict__ w1, const float* __restrict__ w2,
                          const float* __restrict__ w3, const float* __restrict__ wsd,
                          const float* __restrict__ b1, const float* __restrict__ b2,
                          const float* __restrict__ b3, const float* __restrict__ bs,
                          char* __restrict__ wsb) {
    const float* sc = (const float*)(wsb + WS_SCALES);
    int mode = blockIdx.y;
    int i0 = blockIdx.x * 256 + threadIdx.x;
    int stride = gridDim.x * 256;
    if (mode == 0) {
        float s = sc[0]; signed char* o = (signed char*)(wsb + WS_W1Q);
        for (int i = i0; i < 131072; i += stride)
            o[i] = (signed char)(int)rintf(fminf(fmaxf(w1[i] / s, -1.f), 1.f) * 127.f);
    } else if (mode == 1) {
        float s = sc[1]; signed char* o = (signed char*)(wsb + WS_W2Q);
        for (int i = i0; i < 589824; i += stride) {
            int oo = i / 2304, r2 = i - oo * 2304;
            int c = r2 / 9, kk = r2 - c * 9;
            o[(size_t)oo * 2304 + kk * 256 + c] =
                (signed char)(int)rintf(fminf(fmaxf(w2[i] / s, -1.f), 1.f) * 127.f);
        }
    } else if (mode == 2) {
        float s = sc[2]; signed char* o = (signed char*)(wsb + WS_W3Q);
        for (int i = i0; i < 262144; i += stride)
            o[i] = (signed char)(int)rintf(fminf(fmaxf(w3[i] / s, -1.f), 1.f) * 127.f);
    } else if (mode == 3) {
        float s = sc[3]; signed char* o = (signed char*)(wsb + WS_WSQ);
        for (int i = i0; i < 524288; i += stride)
            o[i] = (signed char)(int)rintf(fminf(fmaxf(wsd[i] / s, -1.f), 1.f) * 127.f);
    } else if (mode == 4) {
        float* o = (float*)(wsb + WS_BI1);
        for (int i = i0; i < 256; i += stride) o[i] = rintf(b1[i] * 127.f);
    } else if (mode == 5) {
        float* o = (float*)(wsb + WS_BI2);
        for (int i = i0; i < 256; i += stride) o[i] = rintf(b2[i] * 127.f);
    } else if (mode == 6) {
        float* o = (float*)(wsb + WS_BI3);
        for (int i = i0; i < 1024; i += stride) o[i] = rintf(b3[i] * 127.f);
    } else {
        float* o = (float*)(wsb + WS_BIS);
        for (int i = i0; i < 1024; i += stride) o[i] = rintf(bs[i] * 127.f);
    }
}

// quantize + transpose x: float [64][512][784] -> int8 a0 [64*784][512]
// float4 loads (16B/lane), 32c x 128p tiles
__global__ __launch_bounds__(256) void k_quant_x(const float* __restrict__ x,
                                                 signed char* __restrict__ a0) {
    __shared__ signed char tile[32][132];
    int b = blockIdx.z;
    int p0 = blockIdx.x * 128, c0 = blockIdx.y * 32;
    int tc = threadIdx.x >> 3;            // channel within tile (0..31)
    int pq = (threadIdx.x & 7) * 16;      // p offset (0..112)
    const float* xr = x + ((size_t)b * 512 + c0 + tc) * 784 + p0 + pq;
#pragma unroll
    for (int u = 0; u < 4; u++) {
        int p = p0 + pq + u * 4;
        f32x4 v = {0.f, 0.f, 0.f, 0.f};
        if (p < 784) v = *(const f32x4*)(xr + u * 4);   // 784%4==0: whole-vec predicate
        signed char q[4];
#pragma unroll
        for (int e = 0; e < 4; e++) {
            float f = fminf(fmaxf(v[e] * 2.f, -1.f), 1.f);
            q[e] = (signed char)(int)rintf(f * 127.f);
        }
        *(int*)&tile[tc][pq + u * 4] = *(int*)q;
    }
    __syncthreads();
#pragma unroll
    for (int u = 0; u < 4; u++) {
        int idx = threadIdx.x + u * 256;
        int pp = idx >> 3, cs = (idx & 7) * 4;
        if (p0 + pp < 784) {
            unsigned pk = 0;
#pragma unroll
            for (int i = 0; i < 4; i++)
                pk |= (unsigned)(unsigned char)tile[cs + i][pp] << (8 * i);
            *(unsigned*)(a0 + ((size_t)b * 784 + p0 + pp) * 512 + c0 + cs) = pk;
        }
    }
}

// ---------- i8-MFMA GEMM kernels: A direct-to-reg, B staged via global_load_lds ----------
// MODE 0: conv1  M=256 K=512  Nflat=50176 -> a1 int8 [n][256]
// MODE 1: conv2  M=256 K=2304 Nflat=12544 (im2col 3x3/s2/p1 gather) -> a2 int8 [n][256]
// MODE 2: conv3 (t<4: K=256 a2) + shortcut (t>=4: K=512 a0 strided) -> float out NCHW
//
// A (weights, 128-576KB, L2-hot): per-lane global_load_dwordx4 fragments,
// 1-step register prefetch (aC/aN, statically indexed). The lane fragment
// A[m][t*64+quad*16] is byte-identical to what the old staged path delivered.
// B (activations): gll16 into 3 rotating LDS buffers, source-side bank swizzle
// (rule #21), counted vmcnt + raw s_barrier.
//
// ORDER-PROOF vmcnt derivation (r4 post-mortem: never assume intra-region
// vmem issue order):
//  * prologue [stageB(0), stageB(1), loadA(0)] ends with vmcnt(0): a full
//    drain is correct under ANY order. One-time cost per block.
//  * each sub-iter region issues exactly FM A-loads + NI_B B-stages (internal
//    order irrelevant). At the bar guarding buf[s], the newest FM+NI_B ops
//    are the single region issued since B(s)'s region ended, so
//    vmcnt(FM+NI_B) retires B(s) while keeping B(s+1) and A(s+1) in flight.
//  * final bar: the region before it has no stage -> newest FM ops are
//    A(last); vmcnt(FM) retires B(last).
//  * MFMA's A-operand wait is compiler-inserted (exact, in-order; retires
//    nothing issued after the A load). sched_barrier(0) between loadA and
//    stageB pins issue order so that wait does not also retire the B
//    prefetch (perf-only; correctness holds either way).
template <int MODE, int BM, int BN, int WGM, int WGN>
__global__ __launch_bounds__(256) void k_conv(char* __restrict__ wsb, float* __restrict__ dout) {
    constexpr int FM = BM / WGM / 16;
    constexpr int FN = BN / WGN / 16;
    constexpr int SB = BN / 16;                      // staged B row-blocks
    constexpr int NI_B = SB / 4;                     // gll per wave per step
    constexpr int KTOT = (MODE == 0) ? 512 : (MODE == 1) ? 2304 : 768;
    constexpr int NSTEP = KTOT / 64;
    constexpr int BMP = BM + 16;                     // padded epi stride (int8 modes)
    constexpr int LDS_STAGE = BN * 64;               // one staging buffer (B only)
    constexpr int LDS_EPI = (MODE == 2) ? 64 * (BN + 4) * 4 : BN * BMP;
    constexpr int LDSZ = (3 * LDS_STAGE > LDS_EPI) ? 3 * LDS_STAGE : LDS_EPI;
    static_assert(FM + NI_B == 6 || FM + NI_B == 4, "steady bar count");
    static_assert(FM == 4 || FM == 2, "tail bar count");
    static_assert(NSTEP % 2 == 0, "even steps");

    __shared__ alignas(16) char lds[LDSZ];

    const int tid = threadIdx.x;
    const int wid = tid >> 6;
    const int lane = tid & 63;
    const int n0 = blockIdx.x * BN;
    const int m0 = blockIdx.y * BM;
    const int bb = blockIdx.z;

    const float* sc = (const float*)(wsb + WS_SCALES);
    const int srow = lane >> 2;
    const int lrow = lane & 15;
    const int quad = lane >> 4;
    const int wm = (wid % WGM) * (BM / WGM);
    const int wn = (wid / WGM) * (BN / WGN);
    // source-side chunk swizzle for staged B (dest linear, src XOR'd)
    const int xco = ((lane & 3) ^ ((lane >> 3) & 3)) << 4;
    const char* zp = wsb + WS_ZERO + xco;

    // ---- A fragment base pointers (k=0); weights, L2-resident ----
    const char* aB[FM];
    const char* aB2[FM];                             // MODE 2 shortcut weights
#pragma unroll
    for (int i = 0; i < FM; i++) {
        int m = m0 + wm + i * 16 + lrow;
        if constexpr (MODE == 0) {
            aB[i] = wsb + WS_W1Q + (size_t)m * 512 + quad * 16;
        } else if constexpr (MODE == 1) {
            aB[i] = wsb + WS_W2Q + (size_t)m * 2304 + quad * 16;
        } else {
            aB[i]  = wsb + WS_W3Q + (size_t)m * 256 + quad * 16;
            aB2[i] = wsb + WS_WSQ + (size_t)m * 512 + quad * 16;
        }
    }

    int4v acc3[FM][FN] = {};
    int4v accS[FM][FN] = {};

    auto srcB = [&](int s, int k0) -> const char* {
        int n = n0 + s * 16 + srow;
        const char* g = zp;
        if constexpr (MODE == 0) {
            g = wsb + WS_A0 + (size_t)n * 512 + k0 + xco;
        } else if constexpr (MODE == 1) {
            unsigned b = (unsigned)n / 196u;
            unsigned hw = (unsigned)n - b * 196u;
            int oh = hw / 14, ow = hw - oh * 14;
            int tap = k0 >> 8;
            int kh = tap / 3, kw = tap - kh * 3;
            int c0 = k0 & 255;
            int ih = 2 * oh - 1 + kh, iw = 2 * ow - 1 + kw;
            if (ih >= 0 && ih < 28 && iw >= 0 && iw < 28)
                g = wsb + WS_A1 + ((size_t)b * 784 + ih * 28 + iw) * 256 + c0 + xco;
        } else {
            if (n < 196) {
                if (k0 < 256) {
                    g = wsb + WS_A2 + ((size_t)bb * 196 + n) * 256 + k0 + xco;
                } else {
                    int oh = n / 14, ow = n - oh * 14;
                    int ps = oh * 56 + ow * 2;
                    g = wsb + WS_A0 + ((size_t)bb * 784 + ps) * 512 + (k0 - 256) + xco;
                }
            }
        }
        return g;
    };

    auto stageB = [&](int t, char* buf) {
        const int k0 = t * 64;
#pragma unroll
        for (int ii = 0; ii < NI_B; ii++) {
            const int s = wid + ii * 4;
            gll16(srcB(s, k0), buf + s * 1024);      // lds dest wave-uniform, linear
        }
    };

    auto loadA = [&](int t, int4v (&a)[FM]) {
        if constexpr (MODE == 2) {
            if (t < 4) {
                const int off = t * 64;
#pragma unroll
                for (int i = 0; i < FM; i++) a[i] = *(const int4v*)(aB[i] + off);
            } else {
                const int off = (t - 4) * 64;
#pragma unroll
                for (int i = 0; i < FM; i++) a[i] = *(const int4v*)(aB2[i] + off);
            }
        } else {
            const int off = t * 64;
#pragma unroll
            for (int i = 0; i < FM; i++) a[i] = *(const int4v*)(aB[i] + off);
        }
    };

    auto dsB = [&](const char* cur, int4v (&b)[FN]) {
#pragma unroll
        for (int j = 0; j < FN; j++) {
            int n = wn + j * 16 + lrow;
            b[j] = *(const int4v*)(cur + n * 64 + ((quad ^ ((n >> 1) & 3)) << 4));
        }
    };

    auto MF = [&](int4v (&ac)[FM][FN], int4v (&a)[FM], int4v (&b)[FN]) {
#pragma unroll
        for (int i = 0; i < FM; i++)
#pragma unroll
            for (int j = 0; j < FN; j++)
                ac[i][j] = __builtin_amdgcn_mfma_i32_16x16x64_i8(a[i], b[j], ac[i][j], 0, 0, 0);
    };

    int4v aC[FM], aN[FM], bfr[FN];
    stageB(0, lds);
    stageB(1, lds + LDS_STAGE);
    loadA(0, aC);
    VMCNT_BAR(0);                                    // prologue drain: order-proof

    for (int t = 0; t < NSTEP; t += 2) {
        // ---- even sub-iter t: consume aC + buf[t%3] ----
        loadA(t + 1, aN);
        __builtin_amdgcn_sched_barrier(0);           // keep A-issue before B-stage
        if (t + 2 < NSTEP) stageB(t + 2, lds + ((t + 2) % 3) * LDS_STAGE);
        dsB(lds + (t % 3) * LDS_STAGE, bfr);
        if (MODE != 2 || t < 4) MF(acc3, aC, bfr); else MF(accS, aC, bfr);
        if (t + 1 == NSTEP - 1) {
            if constexpr (FM == 4) VMCNT_BAR(4); else VMCNT_BAR(2);
        } else {
            if constexpr (FM + NI_B == 6) VMCNT_BAR(6); else VMCNT_BAR(4);
        }

        // ---- odd sub-iter t+1: consume aN + buf[(t+1)%3] ----
        if (t + 2 < NSTEP) loadA(t + 2, aC);
        __builtin_amdgcn_sched_barrier(0);
        if (t + 3 < NSTEP) stageB(t + 3, lds + ((t + 3) % 3) * LDS_STAGE);
        dsB(lds + ((t + 1) % 3) * LDS_STAGE, bfr);
        if (MODE != 2 || t + 1 < 4) MF(acc3, aN, bfr); else MF(accS, aN, bfr);
        if (t + 2 < NSTEP) {
            if constexpr (FM + NI_B == 6) VMCNT_BAR(6); else VMCNT_BAR(4);
        }
    }

    // ---------------- epilogue (C/D map: col=lane&15, row=quad*4+reg) ----------------
    if constexpr (MODE == 0 || MODE == 1) {
        const float alpha = sc[MODE] / 16129.0f;
        const float* bi = (const float*)(wsb + (MODE == 0 ? WS_BI1 : WS_BI2));
        signed char* outp = (signed char*)(wsb + (MODE == 0 ? WS_A1 : WS_A2));
        __syncthreads();   // staging reads finished everywhere; reuse lds for epi
#pragma unroll
        for (int i = 0; i < FM; i++) {
            int mloc = wm + i * 16 + quad * 4;      // local m of r=0
            int mb = m0 + mloc;
            float bt[4];
#pragma unroll
            for (int r = 0; r < 4; r++) bt[r] = bi[mb + r] * (2.0f / 127.0f);
#pragma unroll
            for (int j = 0; j < FN; j++) {
                int nloc = wn + j * 16 + lrow;
                unsigned pk = 0;
#pragma unroll
                for (int r = 0; r < 4; r++) {
                    float v = alpha * (float)acc3[i][j][r] + bt[r];
                    int q = (int)rintf(127.0f * fminf(fmaxf(2.0f * v, 0.0f), 1.0f));
                    pk |= (unsigned)(q & 0xFF) << (8 * r);
                }
                *(unsigned*)(lds + nloc * BMP + mloc) = pk;
            }
        }
        __syncthreads();
        // coalesced copy-out: full 64B-line coverage, rows are [n][256] m-contig
        for (int u = tid; u < BN * (BM / 16); u += 256) {
            int row = u / (BM / 16);
            int seg = u % (BM / 16);
            uint4 v = *(const uint4*)(lds + row * BMP + seg * 16);
            *(uint4*)(outp + (size_t)(n0 + row) * 256 + m0 + seg * 16) = v;
        }
    } else {
        const float c2 = sc[1], c3 = sc[2], cS = sc[3];
        const float* bi3 = (const float*)(wsb + WS_BI3);
        const float* bis = (const float*)(wsb + WS_BIS);
        float* ldsF = (float*)lds;
        constexpr int LDN = BN + 4;
        constexpr int SEGS = BN / 16;
        for (int half = 0; half < 2; half++) {
            __syncthreads();
            if (wm == half * 64) {
#pragma unroll
                for (int i = 0; i < FM; i++) {
                    int mloc = i * 16 + quad * 4;           // within half [0,64)
                    int mg = m0 + half * 64 + mloc;         // global m
                    float bt[4];
#pragma unroll
                    for (int r = 0; r < 4; r++)
                        bt[r] = bi3[mg + r] * (c3 / (127.0f * c2)) + bis[mg + r] * (1.0f / 127.0f);
#pragma unroll
                    for (int j = 0; j < FN; j++) {
                        int nloc = wn + j * 16 + lrow;
#pragma unroll
                        for (int r = 0; r < 4; r++) {
                            float v = (c3 * (float)acc3[i][j][r] + cS * (float)accS[i][j][r])
                                          * (0.5f / 16129.0f) + bt[r];
                            v = v < 0.0f ? 0.0f : (v > 6.0f ? 6.0f : v);  // NaN-propagating
                            ldsF[(mloc + r) * LDN + nloc] = v;
                        }
                    }
                }
            }
            __syncthreads();
            // copy out 64 rows x BN floats (aligned 16B segments along n)
            {
                int rw0 = tid / SEGS, seg = tid % SEGS;
                int nbase = n0 + seg * 16;
                for (int row = rw0; row < 64; row += 256 / SEGS) {
                    const float* src = ldsF + row * LDN + seg * 16;
                    float* dst = dout + ((size_t)bb * 1024 + m0 + half * 64 + row) * 196 + nbase;
                    if (nbase + 16 <= 196) {
                        *(f32x4*)(dst + 0)  = *(const f32x4*)(src + 0);
                        *(f32x4*)(dst + 4)  = *(const f32x4*)(src + 4);
                        *(f32x4*)(dst + 8)  = *(const f32x4*)(src + 8);
                        *(f32x4*)(dst + 12) = *(const f32x4*)(src + 12);
                    } else {
                        for (int q = 0; q < 16 && nbase + q < 196; q++) dst[q] = src[q];
                    }
                }
            }
        }
    }
}

extern "C" void kernel_launch(void* const* d_in, const int* in_sizes, int n_in,
                              void* d_out, int out_size, void* d_ws, size_t ws_size,
                              hipStream_t stream) {
    const float* x   = (const float*)d_in[0];
    const float* w1  = (const float*)d_in[1];
    const float* b1  = (const float*)d_in[2];
    const float* w2  = (const float*)d_in[3];
    const float* b2  = (const float*)d_in[4];
    const float* w3  = (const float*)d_in[5];
    const float* b3  = (const float*)d_in[6];
    const float* wsd = (const float*)d_in[7];
    const float* bs  = (const float*)d_in[8];
    float* out = (float*)d_out;
    char* wsb = (char*)d_ws;

    k_init<<<16, 256, 0, stream>>>((float*)wsb);
    k_maxabs<<<dim3(128, 4), 256, 0, stream>>>(w1, w2, w3, wsd, (float*)(wsb + WS_SCALES));
    k_quant_w<<<dim3(96, 8), 256, 0, stream>>>(w1, w2, w3, wsd, b1, b2, b3, bs, wsb);
    k_quant_x<<<dim3(7, 16, 64), 256, 0, stream>>>(x, (signed char*)(wsb + WS_A0));
    k_conv<0, 128, 128, 2, 2><<<dim3(392, 2, 1), 256, 0, stream>>>(wsb, out);  // conv1
    k_conv<1, 64, 128, 2, 2><<<dim3(98, 4, 1), 256, 0, stream>>>(wsb, out);    // conv2
    k_conv<2, 128, 128, 2, 2><<<dim3(2, 8, 64), 256, 0, stream>>>(wsb, out);   // conv3+sc
}

// Round 6
// 333.896 us; speedup vs baseline: 1.2306x; 1.0030x over previous
//
#include <hip/hip_runtime.h>
#include <stdint.h>

typedef int   int4v __attribute__((ext_vector_type(4)));
typedef float f32x4 __attribute__((ext_vector_type(4)));

// ---- workspace layout (bytes) ----
#define WS_SCALES 0ull
#define WS_ZERO   256ull
#define WS_BI1    1024ull
#define WS_BI2    2048ull
#define WS_BI3    4096ull
#define WS_BIS    8192ull
#define WS_W1Q    16384ull                     // int8 [256][512]
#define WS_W2Q    (WS_W1Q + 131072ull)         // int8 [256][2304]  k=(kh*3+kw)*256+c
#define WS_W3Q    (WS_W2Q + 589824ull)         // int8 [1024][256]
#define WS_WSQ    (WS_W3Q + 262144ull)         // int8 [1024][512]
#define WS_A0     2097152ull                   // int8 [50176][512]  (= [64][784][512])
#define WS_A1     (WS_A0 + 25690112ull)        // int8 [50176][256]
#define WS_A2     (WS_A1 + 12845056ull)        // int8 [12544][256]  (= [64][196][256])

__device__ __forceinline__ void gll16(const void* g, void* l) {
    // async global -> LDS, 16B/lane, dest = wave-uniform base + lane*16
    __builtin_amdgcn_global_load_lds((const __attribute__((address_space(1))) void*)g,
                                     (__attribute__((address_space(3))) void*)l, 16, 0, 0);
}

// counted-wait + raw barrier: leave n vmem ops in flight across the barrier.
#define VMCNT_BAR(n) asm volatile("s_waitcnt vmcnt(" #n ")\n\ts_barrier" ::: "memory")

__global__ void k_init(float* wshead) {
    int i = blockIdx.x * 256 + threadIdx.x;
    wshead[i] = 0.0f;   // 16 blocks x 256 = 16 KB: scales+zero page+biases
}

__global__ void k_maxabs(const float* __restrict__ w1, const float* __restrict__ w2,
                         const float* __restrict__ w3, const float* __restrict__ wsd,
                         float* __restrict__ scales) {
    const float* srcs[4] = {w1, w2, w3, wsd};
    const int n4s[4] = {32768, 147456, 65536, 131072};   // element counts / 4
    int t = blockIdx.y;
    const f32x4* s = (const f32x4*)srcs[t];
    int n4 = n4s[t];
    float m = 0.0f;
    for (int i = blockIdx.x * 256 + threadIdx.x; i < n4; i += gridDim.x * 256) {
        f32x4 v = s[i];
        m = fmaxf(m, fmaxf(fmaxf(fabsf(v[0]), fabsf(v[1])), fmaxf(fabsf(v[2]), fabsf(v[3]))));
    }
    __shared__ float red[256];
    red[threadIdx.x] = m;
    __syncthreads();
    for (int st = 128; st > 0; st >>= 1) {
        if (threadIdx.x < st) red[threadIdx.x] = fmaxf(red[threadIdx.x], red[threadIdx.x + st]);
        __syncthreads();
    }
    if (threadIdx.x == 0) atomicMax((int*)&scales[t], __float_as_int(red[0]));
}

__global__ void k_quant_w(const float* __restrict__ w1, const float* __restrict__ w2,
                          const float* __restrict__ w3, const float* __restrict__ wsd,
                          const float* __restrict__ b1, const float* __restrict__ b2,
                          const float* __restrict__ b3, const float* __restrict__ bs,
                          char* __restrict__ wsb) {
    const float* sc = (const float*)(wsb + WS_SCALES);
    int mode = blockIdx.y;
    int i0 = blockIdx.x * 256 + threadIdx.x;
    int stride = gridDim.x * 256;
    if (mode == 0) {
        float s = sc[0]; signed char* o = (signed char*)(wsb + WS_W1Q);
        for (int i = i0; i < 131072; i += stride)
            o[i] = (signed char)(int)rintf(fminf(fmaxf(w1[i] / s, -1.f), 1.f) * 127.f);
    } else if (mode == 1) {
        float s = sc[1]; signed char* o = (signed char*)(wsb + WS_W2Q);
        for (int i = i0; i < 589824; i += stride) {
            int oo = i / 2304, r2 = i - oo * 2304;
            int c = r2 / 9, kk = r2 - c * 9;
            o[(size_t)oo * 2304 + kk * 256 + c] =
                (signed char)(int)rintf(fminf(fmaxf(w2[i] / s, -1.f), 1.f) * 127.f);
        }
    } else if (mode == 2) {
        float s = sc[2]; signed char* o = (signed char*)(wsb + WS_W3Q);
        for (int i = i0; i < 262144; i += stride)
            o[i] = (signed char)(int)rintf(fminf(fmaxf(w3[i] / s, -1.f), 1.f) * 127.f);
    } else if (mode == 3) {
        float s = sc[3]; signed char* o = (signed char*)(wsb + WS_WSQ);
        for (int i = i0; i < 524288; i += stride)
            o[i] = (signed char)(int)rintf(fminf(fmaxf(wsd[i] / s, -1.f), 1.f) * 127.f);
    } else if (mode == 4) {
        float* o = (float*)(wsb + WS_BI1);
        for (int i = i0; i < 256; i += stride) o[i] = rintf(b1[i] * 127.f);
    } else if (mode == 5) {
        float* o = (float*)(wsb + WS_BI2);
        for (int i = i0; i < 256; i += stride) o[i] = rintf(b2[i] * 127.f);
    } else if (mode == 6) {
        float* o = (float*)(wsb + WS_BI3);
        for (int i = i0; i < 1024; i += stride) o[i] = rintf(b3[i] * 127.f);
    } else {
        float* o = (float*)(wsb + WS_BIS);
        for (int i = i0; i < 1024; i += stride) o[i] = rintf(bs[i] * 127.f);
    }
}

// quantize + transpose x: float [64][512][784] -> int8 a0 [64*784][512]
// float4 loads (16B/lane), 32c x 128p tiles
__global__ __launch_bounds__(256) void k_quant_x(const float* __restrict__ x,
                                                 signed char* __restrict__ a0) {
    __shared__ signed char tile[32][132];
    int b = blockIdx.z;
    int p0 = blockIdx.x * 128, c0 = blockIdx.y * 32;
    int tc = threadIdx.x >> 3;            // channel within tile (0..31)
    int pq = (threadIdx.x & 7) * 16;      // p offset (0..112)
    const float* xr = x + ((size_t)b * 512 + c0 + tc) * 784 + p0 + pq;
#pragma unroll
    for (int u = 0; u < 4; u++) {
        int p = p0 + pq + u * 4;
        f32x4 v = {0.f, 0.f, 0.f, 0.f};
        if (p < 784) v = *(const f32x4*)(xr + u * 4);   // 784%4==0: whole-vec predicate
        signed char q[4];
#pragma unroll
        for (int e = 0; e < 4; e++) {
            float f = fminf(fmaxf(v[e] * 2.f, -1.f), 1.f);
            q[e] = (signed char)(int)rintf(f * 127.f);
        }
        *(int*)&tile[tc][pq + u * 4] = *(int*)q;
    }
    __syncthreads();
#pragma unroll
    for (int u = 0; u < 4; u++) {
        int idx = threadIdx.x + u * 256;
        int pp = idx >> 3, cs = (idx & 7) * 4;
        if (p0 + pp < 784) {
            unsigned pk = 0;
#pragma unroll
            for (int i = 0; i < 4; i++)
                pk |= (unsigned)(unsigned char)tile[cs + i][pp] << (8 * i);
            *(unsigned*)(a0 + ((size_t)b * 784 + p0 + pp) * 512 + c0 + cs) = pk;
        }
    }
}

// ============ ONE-SHOT kernels (conv1 / conv3): whole B-panel fits LDS ============
// Stage ALL of B once (one burst of gll16, one vmcnt(0)+barrier — order-proof),
// A (weights, L2-hot) loaded direct-to-reg per fragment. Zero K-loop barriers:
// latency is paid once per block, not once per K-step. Same data layout, same
// source-side XOR swizzle + read-side XOR, same epilogues => bit-identical.
template <int MODE, int BM, int BN, int WGM, int WGN>
__global__ __launch_bounds__(256) void k_conv_os(char* __restrict__ wsb, float* __restrict__ dout) {
    constexpr int FM = BM / WGM / 16;
    constexpr int FN = BN / WGN / 16;
    constexpr int NI_B = BN / 64;                    // gll per wave per subtile
    constexpr int KTOT = (MODE == 0) ? 512 : 768;
    constexpr int NSTEP = KTOT / 64;
    constexpr int BMP = BM + 16;
    constexpr int LDS_STAGE = BN * 64;               // one K-subtile of B
    constexpr int LDS_ALL = NSTEP * LDS_STAGE;       // 64KB (conv1) / 96KB (conv3)
    constexpr int LDS_EPI = (MODE == 2) ? 64 * (BN + 4) * 4 : BN * BMP;
    constexpr int LDSZ = (LDS_ALL > LDS_EPI) ? LDS_ALL : LDS_EPI;

    __shared__ alignas(16) char lds[LDSZ];

    const int tid = threadIdx.x;
    const int wid = tid >> 6;
    const int lane = tid & 63;
    const int n0 = blockIdx.x * BN;
    const int m0 = blockIdx.y * BM;
    const int bb = blockIdx.z;

    const float* sc = (const float*)(wsb + WS_SCALES);
    const int srow = lane >> 2;
    const int lrow = lane & 15;
    const int quad = lane >> 4;
    const int wm = (wid % WGM) * (BM / WGM);
    const int wn = (wid / WGM) * (BN / WGN);
    const int xco = ((lane & 3) ^ ((lane >> 3) & 3)) << 4;   // source-side swizzle
    const char* zp = wsb + WS_ZERO + xco;

    // ---- A fragment base pointers (weights, L2-resident) ----
    const char* aB[FM];
    const char* aB2[FM];
#pragma unroll
    for (int i = 0; i < FM; i++) {
        int m = m0 + wm + i * 16 + lrow;
        if constexpr (MODE == 0) {
            aB[i] = wsb + WS_W1Q + (size_t)m * 512 + quad * 16;
        } else {
            aB[i]  = wsb + WS_W3Q + (size_t)m * 256 + quad * 16;
            aB2[i] = wsb + WS_WSQ + (size_t)m * 512 + quad * 16;
        }
    }

    // ---- stage ENTIRE B panel, one drain ----
#pragma unroll
    for (int t = 0; t < NSTEP; t++) {
        const int k0 = t * 64;
#pragma unroll
        for (int ii = 0; ii < NI_B; ii++) {
            const int s = wid + ii * 4;
            int n = n0 + s * 16 + srow;
            const char* g = zp;
            if constexpr (MODE == 0) {
                g = wsb + WS_A0 + (size_t)n * 512 + k0 + xco;
            } else {
                if (n < 196) {
                    if (k0 < 256) {
                        g = wsb + WS_A2 + ((size_t)bb * 196 + n) * 256 + k0 + xco;
                    } else {
                        int oh = n / 14, ow = n - oh * 14;
                        int ps = oh * 56 + ow * 2;
                        g = wsb + WS_A0 + ((size_t)bb * 784 + ps) * 512 + (k0 - 256) + xco;
                    }
                }
            }
            gll16(g, lds + t * LDS_STAGE + s * 1024);
        }
    }
    VMCNT_BAR(0);            // full drain before any ds_read: order-proof

    int4v acc3[FM][FN] = {};
    int4v accS[FM][FN] = {};

    // ---- barrier-free compute: full unroll, compiler schedules loads freely ----
#pragma unroll
    for (int t = 0; t < NSTEP; t++) {
        int4v a[FM], b[FN];
        if constexpr (MODE == 2) {
            if (t < 4) {
                const int off = t * 64;
#pragma unroll
                for (int i = 0; i < FM; i++) a[i] = *(const int4v*)(aB[i] + off);
            } else {
                const int off = (t - 4) * 64;
#pragma unroll
                for (int i = 0; i < FM; i++) a[i] = *(const int4v*)(aB2[i] + off);
            }
        } else {
            const int off = t * 64;
#pragma unroll
            for (int i = 0; i < FM; i++) a[i] = *(const int4v*)(aB[i] + off);
        }
        const char* cur = lds + t * LDS_STAGE;
#pragma unroll
        for (int j = 0; j < FN; j++) {
            int n = wn + j * 16 + lrow;
            b[j] = *(const int4v*)(cur + n * 64 + ((quad ^ ((n >> 1) & 3)) << 4));
        }
        if (MODE != 2 || t < 4) {
#pragma unroll
            for (int i = 0; i < FM; i++)
#pragma unroll
                for (int j = 0; j < FN; j++)
                    acc3[i][j] = __builtin_amdgcn_mfma_i32_16x16x64_i8(a[i], b[j], acc3[i][j], 0, 0, 0);
        } else {
#pragma unroll
            for (int i = 0; i < FM; i++)
#pragma unroll
                for (int j = 0; j < FN; j++)
                    accS[i][j] = __builtin_amdgcn_mfma_i32_16x16x64_i8(a[i], b[j], accS[i][j], 0, 0, 0);
        }
    }

    // ---------------- epilogue (C/D map: col=lane&15, row=quad*4+reg) ----------------
    if constexpr (MODE == 0) {
        const float alpha = sc[0] / 16129.0f;
        const float* bi = (const float*)(wsb + WS_BI1);
        signed char* outp = (signed char*)(wsb + WS_A1);
        __syncthreads();   // all LDS reads done everywhere; reuse lds for epi
#pragma unroll
        for (int i = 0; i < FM; i++) {
            int mloc = wm + i * 16 + quad * 4;
            int mb = m0 + mloc;
            float bt[4];
#pragma unroll
            for (int r = 0; r < 4; r++) bt[r] = bi[mb + r] * (2.0f / 127.0f);
#pragma unroll
            for (int j = 0; j < FN; j++) {
                int nloc = wn + j * 16 + lrow;
                unsigned pk = 0;
#pragma unroll
                for (int r = 0; r < 4; r++) {
                    float v = alpha * (float)acc3[i][j][r] + bt[r];
                    int q = (int)rintf(127.0f * fminf(fmaxf(2.0f * v, 0.0f), 1.0f));
                    pk |= (unsigned)(q & 0xFF) << (8 * r);
                }
                *(unsigned*)(lds + nloc * BMP + mloc) = pk;
            }
        }
        __syncthreads();
        for (int u = tid; u < BN * (BM / 16); u += 256) {
            int row = u / (BM / 16);
            int seg = u % (BM / 16);
            uint4 v = *(const uint4*)(lds + row * BMP + seg * 16);
            *(uint4*)(outp + (size_t)(n0 + row) * 256 + m0 + seg * 16) = v;
        }
    } else {
        const float c2 = sc[1], c3 = sc[2], cS = sc[3];
        const float* bi3 = (const float*)(wsb + WS_BI3);
        const float* bis = (const float*)(wsb + WS_BIS);
        float* ldsF = (float*)lds;
        constexpr int LDN = BN + 4;
        constexpr int SEGS = BN / 16;
        for (int half = 0; half < 2; half++) {
            __syncthreads();
            if (wm == half * 64) {
#pragma unroll
                for (int i = 0; i < FM; i++) {
                    int mloc = i * 16 + quad * 4;
                    int mg = m0 + half * 64 + mloc;
                    float bt[4];
#pragma unroll
                    for (int r = 0; r < 4; r++)
                        bt[r] = bi3[mg + r] * (c3 / (127.0f * c2)) + bis[mg + r] * (1.0f / 127.0f);
#pragma unroll
                    for (int j = 0; j < FN; j++) {
                        int nloc = wn + j * 16 + lrow;
#pragma unroll
                        for (int r = 0; r < 4; r++) {
                            float v = (c3 * (float)acc3[i][j][r] + cS * (float)accS[i][j][r])
                                          * (0.5f / 16129.0f) + bt[r];
                            v = v < 0.0f ? 0.0f : (v > 6.0f ? 6.0f : v);  // NaN-propagating
                            ldsF[(mloc + r) * LDN + nloc] = v;
                        }
                    }
                }
            }
            __syncthreads();
            {
                int rw0 = tid / SEGS, seg = tid % SEGS;
                int nbase = n0 + seg * 16;
                for (int row = rw0; row < 64; row += 256 / SEGS) {
                    const float* src = ldsF + row * LDN + seg * 16;
                    float* dst = dout + ((size_t)bb * 1024 + m0 + half * 64 + row) * 196 + nbase;
                    if (nbase + 16 <= 196) {
                        *(f32x4*)(dst + 0)  = *(const f32x4*)(src + 0);
                        *(f32x4*)(dst + 4)  = *(const f32x4*)(src + 4);
                        *(f32x4*)(dst + 8)  = *(const f32x4*)(src + 8);
                        *(f32x4*)(dst + 12) = *(const f32x4*)(src + 12);
                    } else {
                        for (int q = 0; q < 16 && nbase + q < 196; q++) dst[q] = src[q];
                    }
                }
            }
        }
    }
}

// ============ conv2: r2-exact staged kernel (K=2304 doesn't fit LDS) ============
// A+B both staged via gll16, 3 rotating buffers, depth-2 prefetch, counted
// vmcnt(NI=3) + raw s_barrier, final step drains vmcnt(0). Verified in r2.
__global__ __launch_bounds__(256) void k_conv2(char* __restrict__ wsb) {
    constexpr int BM = 64, BN = 128, WGM = 2, WGN = 2;
    constexpr int FM = BM / WGM / 16;                // 2
    constexpr int FN = BN / WGN / 16;                // 4
    constexpr int ISS_A = BM / 16;                   // 4
    constexpr int NI = (BM + BN) / 64;               // 3
    constexpr int NSTEP = 2304 / 64;                 // 36
    constexpr int BMP = BM + 16;
    constexpr int LDS_STAGE = (BM + BN) * 64;        // 12288
    constexpr int LDS_EPI = BN * BMP;                // 10240
    constexpr int LDSZ = 3 * LDS_STAGE;

    __shared__ alignas(16) char lds[LDSZ];

    const int tid = threadIdx.x;
    const int wid = tid >> 6;
    const int lane = tid & 63;
    const int n0 = blockIdx.x * BN;
    const int m0 = blockIdx.y * BM;

    const float* sc = (const float*)(wsb + WS_SCALES);
    const int srow = lane >> 2;
    const int lrow = lane & 15;
    const int quad = lane >> 4;
    const int wm = (wid % WGM) * (BM / WGM);
    const int wn = (wid / WGM) * (BN / WGN);
    const int xco = ((lane & 3) ^ ((lane >> 3) & 3)) << 4;
    const char* zp = wsb + WS_ZERO + xco;

    int4v acc[FM][FN] = {};

    auto src_ptr = [&](int s, int k0) -> const char* {
        const char* g;
        if (s < ISS_A) {
            int m = m0 + s * 16 + srow;
            g = wsb + WS_W2Q + (size_t)m * 2304 + k0 + xco;
        } else {
            int n = n0 + (s - ISS_A) * 16 + srow;
            g = zp;
            unsigned b = (unsigned)n / 196u;
            unsigned hw = (unsigned)n - b * 196u;
            int oh = hw / 14, ow = hw - oh * 14;
            int tap = k0 >> 8;
            int kh = tap / 3, kw = tap - kh * 3;
            int c0 = k0 & 255;
            int ih = 2 * oh - 1 + kh, iw = 2 * ow - 1 + kw;
            if (ih >= 0 && ih < 28 && iw >= 0 && iw < 28)
                g = wsb + WS_A1 + ((size_t)b * 784 + ih * 28 + iw) * 256 + c0 + xco;
        }
        return g;
    };

    auto stage = [&](int t, char* buf) {
        const int k0 = t * 64;
#pragma unroll
        for (int ii = 0; ii < NI; ii++) {
            const int s = wid + ii * 4;
            gll16(src_ptr(s, k0), buf + s * 1024);
        }
    };

    stage(0, lds);
    stage(1, lds + LDS_STAGE);                       // depth-2 prefetch
    for (int t = 0; t < NSTEP; ++t) {
        char* cur = lds + (t % 3) * LDS_STAGE;
        if (t == NSTEP - 1) {
            VMCNT_BAR(0);
        } else {
            VMCNT_BAR(3);                            // tile t done; t+1's 3 in flight
        }
        if (t + 2 < NSTEP) stage(t + 2, lds + ((t + 2) % 3) * LDS_STAGE);

        int4v afr[FM], bfr[FN];
#pragma unroll
        for (int i = 0; i < FM; i++) {
            int m = wm + i * 16 + lrow;
            afr[i] = *(const int4v*)(cur + m * 64 + ((quad ^ ((m >> 1) & 3)) << 4));
        }
#pragma unroll
        for (int j = 0; j < FN; j++) {
            int n = wn + j * 16 + lrow;
            bfr[j] = *(const int4v*)(cur + (BM + n) * 64 + ((quad ^ ((n >> 1) & 3)) << 4));
        }
#pragma unroll
        for (int i = 0; i < FM; i++)
#pragma unroll
            for (int j = 0; j < FN; j++)
                acc[i][j] = __builtin_amdgcn_mfma_i32_16x16x64_i8(afr[i], bfr[j], acc[i][j], 0, 0, 0);
    }

    // epilogue -> a2 int8 [n][256]
    const float alpha = sc[1] / 16129.0f;
    const float* bi = (const float*)(wsb + WS_BI2);
    signed char* outp = (signed char*)(wsb + WS_A2);
    __syncthreads();
#pragma unroll
    for (int i = 0; i < FM; i++) {
        int mloc = wm + i * 16 + quad * 4;
        int mb = m0 + mloc;
        float bt[4];
#pragma unroll
        for (int r = 0; r < 4; r++) bt[r] = bi[mb + r] * (2.0f / 127.0f);
#pragma unroll
        for (int j = 0; j < FN; j++) {
            int nloc = wn + j * 16 + lrow;
            unsigned pk = 0;
#pragma unroll
            for (int r = 0; r < 4; r++) {
                float v = alpha * (float)acc[i][j][r] + bt[r];
                int q = (int)rintf(127.0f * fminf(fmaxf(2.0f * v, 0.0f), 1.0f));
                pk |= (unsigned)(q & 0xFF) << (8 * r);
            }
            *(unsigned*)(lds + nloc * BMP + mloc) = pk;
        }
    }
    __syncthreads();
    for (int u = tid; u < BN * (BM / 16); u += 256) {
        int row = u / (BM / 16);
        int seg = u % (BM / 16);
        uint4 v = *(const uint4*)(lds + row * BMP + seg * 16);
        *(uint4*)(outp + (size_t)(n0 + row) * 256 + m0 + seg * 16) = v;
    }
}

extern "C" void kernel_launch(void* const* d_in, const int* in_sizes, int n_in,
                              void* d_out, int out_size, void* d_ws, size_t ws_size,
                              hipStream_t stream) {
    const float* x   = (const float*)d_in[0];
    const float* w1  = (const float*)d_in[1];
    const float* b1  = (const float*)d_in[2];
    const float* w2  = (const float*)d_in[3];
    const float* b2  = (const float*)d_in[4];
    const float* w3  = (const float*)d_in[5];
    const float* b3  = (const float*)d_in[6];
    const float* wsd = (const float*)d_in[7];
    const float* bs  = (const float*)d_in[8];
    float* out = (float*)d_out;
    char* wsb = (char*)d_ws;

    k_init<<<16, 256, 0, stream>>>((float*)wsb);
    k_maxabs<<<dim3(128, 4), 256, 0, stream>>>(w1, w2, w3, wsd, (float*)(wsb + WS_SCALES));
    k_quant_w<<<dim3(96, 8), 256, 0, stream>>>(w1, w2, w3, wsd, b1, b2, b3, bs, wsb);
    k_quant_x<<<dim3(7, 16, 64), 256, 0, stream>>>(x, (signed char*)(wsb + WS_A0));
    k_conv_os<0, 128, 128, 2, 2><<<dim3(392, 2, 1), 256, 0, stream>>>(wsb, out);  // conv1
    k_conv2<<<dim3(98, 4, 1), 256, 0, stream>>>(wsb);                             // conv2
    k_conv_os<2, 128, 128, 2, 2><<<dim3(2, 8, 64), 256, 0, stream>>>(wsb, out);   // conv3+sc
}

// Round 8
// 299.807 us; speedup vs baseline: 1.3705x; 1.1137x over previous
//
#include <hip/hip_runtime.h>
#include <stdint.h>

typedef int   int4v __attribute__((ext_vector_type(4)));
typedef float f32x4 __attribute__((ext_vector_type(4)));

// ---- workspace layout (bytes) ----
#define WS_SCALES 0ull
#define WS_ZERO   256ull
#define WS_BI1    1024ull
#define WS_BI2    2048ull
#define WS_BI3    4096ull
#define WS_BIS    8192ull
#define WS_W1Q    16384ull                     // int8 [256][512]
#define WS_W2Q    (WS_W1Q + 131072ull)         // int8 [256][2304]  k=(kh*3+kw)*256+c
#define WS_W3Q    (WS_W2Q + 589824ull)         // int8 [1024][256]
#define WS_WSQ    (WS_W3Q + 262144ull)         // int8 [1024][512]
#define WS_A0     2097152ull                   // int8 [50176][512]  (= [64][784][512])
#define WS_A1     (WS_A0 + 25690112ull)        // int8 [50176][256]
#define WS_A2     (WS_A1 + 12845056ull)        // int8 [12544][256]  (= [64][196][256])

__device__ __forceinline__ void gll16(const void* g, void* l) {
    // async global -> LDS, 16B/lane, dest = wave-uniform base + lane*16
    __builtin_amdgcn_global_load_lds((const __attribute__((address_space(1))) void*)g,
                                     (__attribute__((address_space(3))) void*)l, 16, 0, 0);
}

// counted vmem wait + FULL lgkm drain + barrier.
// lgkmcnt(0) makes the 3-buffer rotation schedule-proof (rule #18): every wave's
// ds_reads are complete IN REGISTERS before it passes the barrier, so the
// buffer overwritten by the post-barrier stage() provably has no pending
// readers, regardless of where the compiler placed the MFMAs.
#define VMCNT_BAR(n) asm volatile("s_waitcnt vmcnt(" #n ") lgkmcnt(0)\n\ts_barrier" ::: "memory")

__global__ void k_init(float* wshead) {
    int i = blockIdx.x * 256 + threadIdx.x;
    wshead[i] = 0.0f;   // 16 blocks x 256 = 16 KB: scales+zero page+biases
}

__global__ void k_maxabs(const float* __restrict__ w1, const float* __restrict__ w2,
                         const float* __restrict__ w3, const float* __restrict__ wsd,
                         float* __restrict__ scales) {
    const float* srcs[4] = {w1, w2, w3, wsd};
    const int n4s[4] = {32768, 147456, 65536, 131072};   // element counts / 4
    int t = blockIdx.y;
    const f32x4* s = (const f32x4*)srcs[t];
    int n4 = n4s[t];
    float m = 0.0f;
    for (int i = blockIdx.x * 256 + threadIdx.x; i < n4; i += gridDim.x * 256) {
        f32x4 v = s[i];
        m = fmaxf(m, fmaxf(fmaxf(fabsf(v[0]), fabsf(v[1])), fmaxf(fabsf(v[2]), fabsf(v[3]))));
    }
    __shared__ float red[256];
    red[threadIdx.x] = m;
    __syncthreads();
    for (int st = 128; st > 0; st >>= 1) {
        if (threadIdx.x < st) red[threadIdx.x] = fmaxf(red[threadIdx.x], red[threadIdx.x + st]);
        __syncthreads();
    }
    if (threadIdx.x == 0) atomicMax((int*)&scales[t], __float_as_int(red[0]));
}

__global__ void k_quant_w(const float* __restrict__ w1, const float* __restrict__ w2,
                          const float* __restrict__ w3, const float* __restrict__ wsd,
                          const float* __restrict__ b1, const float* __restrict__ b2,
                          const float* __restrict__ b3, const float* __restrict__ bs,
                          char* __restrict__ wsb) {
    const float* sc = (const float*)(wsb + WS_SCALES);
    int mode = blockIdx.y;
    int i0 = blockIdx.x * 256 + threadIdx.x;
    int stride = gridDim.x * 256;
    if (mode == 0) {
        float s = sc[0]; signed char* o = (signed char*)(wsb + WS_W1Q);
        for (int i = i0; i < 131072; i += stride)
            o[i] = (signed char)(int)rintf(fminf(fmaxf(w1[i] / s, -1.f), 1.f) * 127.f);
    } else if (mode == 1) {
        float s = sc[1]; signed char* o = (signed char*)(wsb + WS_W2Q);
        for (int i = i0; i < 589824; i += stride) {
            int oo = i / 2304, r2 = i - oo * 2304;
            int c = r2 / 9, kk = r2 - c * 9;
            o[(size_t)oo * 2304 + kk * 256 + c] =
                (signed char)(int)rintf(fminf(fmaxf(w2[i] / s, -1.f), 1.f) * 127.f);
        }
    } else if (mode == 2) {
        float s = sc[2]; signed char* o = (signed char*)(wsb + WS_W3Q);
        for (int i = i0; i < 262144; i += stride)
            o[i] = (signed char)(int)rintf(fminf(fmaxf(w3[i] / s, -1.f), 1.f) * 127.f);
    } else if (mode == 3) {
        float s = sc[3]; signed char* o = (signed char*)(wsb + WS_WSQ);
        for (int i = i0; i < 524288; i += stride)
            o[i] = (signed char)(int)rintf(fminf(fmaxf(wsd[i] / s, -1.f), 1.f) * 127.f);
    } else if (mode == 4) {
        float* o = (float*)(wsb + WS_BI1);
        for (int i = i0; i < 256; i += stride) o[i] = rintf(b1[i] * 127.f);
    } else if (mode == 5) {
        float* o = (float*)(wsb + WS_BI2);
        for (int i = i0; i < 256; i += stride) o[i] = rintf(b2[i] * 127.f);
    } else if (mode == 6) {
        float* o = (float*)(wsb + WS_BI3);
        for (int i = i0; i < 1024; i += stride) o[i] = rintf(b3[i] * 127.f);
    } else {
        float* o = (float*)(wsb + WS_BIS);
        for (int i = i0; i < 1024; i += stride) o[i] = rintf(bs[i] * 127.f);
    }
}

// quantize + transpose x: float [64][512][784] -> int8 a0 [64*784][512]
// float4 loads (16B/lane), 32c x 128p tiles
__global__ __launch_bounds__(256) void k_quant_x(const float* __restrict__ x,
                                                 signed char* __restrict__ a0) {
    __shared__ signed char tile[32][132];
    int b = blockIdx.z;
    int p0 = blockIdx.x * 128, c0 = blockIdx.y * 32;
    int tc = threadIdx.x >> 3;            // channel within tile (0..31)
    int pq = (threadIdx.x & 7) * 16;      // p offset (0..112)
    const float* xr = x + ((size_t)b * 512 + c0 + tc) * 784 + p0 + pq;
#pragma unroll
    for (int u = 0; u < 4; u++) {
        int p = p0 + pq + u * 4;
        f32x4 v = {0.f, 0.f, 0.f, 0.f};
        if (p < 784) v = *(const f32x4*)(xr + u * 4);   // 784%4==0: whole-vec predicate
        signed char q[4];
#pragma unroll
        for (int e = 0; e < 4; e++) {
            float f = fminf(fmaxf(v[e] * 2.f, -1.f), 1.f);
            q[e] = (signed char)(int)rintf(f * 127.f);
        }
        *(int*)&tile[tc][pq + u * 4] = *(int*)q;
    }
    __syncthreads();
#pragma unroll
    for (int u = 0; u < 4; u++) {
        int idx = threadIdx.x + u * 256;
        int pp = idx >> 3, cs = (idx & 7) * 4;
        if (p0 + pp < 784) {
            unsigned pk = 0;
#pragma unroll
            for (int i = 0; i < 4; i++)
                pk |= (unsigned)(unsigned char)tile[cs + i][pp] << (8 * i);
            *(unsigned*)(a0 + ((size_t)b * 784 + p0 + pp) * 512 + c0 + cs) = pk;
        }
    }
}

// ---------- i8-MFMA GEMM kernels (r2-proven schedule, 64x64 tiles for residency) ----------
// MODE 0: conv1  M=256 K=512  Nflat=50176 -> a1 int8 [n][256]
// MODE 1: conv2  M=256 K=2304 Nflat=12544 (im2col 3x3/s2/p1 gather) -> a2 int8 [n][256]
// MODE 2: conv3 (t<4: K=256 a2) + shortcut (t>=4: K=512 a0 strided) -> float out NCHW
//
// Both operands staged via gll16 (the ONLY vmem in the K-loop -> counted vmcnt is
// order-proof), 3 rotating LDS buffers, depth-2 prefetch, steady VMCNT_BAR(2)
// (tile t's 2 loads retired; t+1's 2 stay in flight), final VMCNT_BAR(0).
// Every barrier also drains lgkmcnt(0) -> LDS-read-before-overwrite invariant is
// schedule-independent (r7 post-mortem / rule #18).
// 64x64 tile: acc 16-32 VGPR, LDS 24KB, __launch_bounds__(256,4) caps VGPR at 128
// -> 4 waves/SIMD, ~4 blocks/CU resident: phases of different blocks stagger, so
// stage/compute/epilogue overlap across blocks.
template <int MODE>
__global__ __launch_bounds__(256, 4) void k_conv(char* __restrict__ wsb, float* __restrict__ dout) {
    constexpr int BM = 64, BN = 64, WGM = 2;
    constexpr int FM = 2, FN = 2;
    constexpr int ISS_A = BM / 16;                   // 4 A row-blocks
    constexpr int NI = (BM + BN) / 64;               // 2 gll per wave per step
    constexpr int KTOT = (MODE == 0) ? 512 : (MODE == 1) ? 2304 : 768;
    constexpr int NSTEP = KTOT / 64;
    constexpr int BMP = BM + 16;                     // padded epi stride (int8 modes)
    constexpr int LDS_STAGE = (BM + BN) * 64;        // 8KB
    constexpr int LDSZ = 3 * LDS_STAGE;              // 24KB (mode2 epi 64*68*4=17.4KB fits)

    __shared__ alignas(16) char lds[LDSZ];

    const int tid = threadIdx.x;
    const int wid = tid >> 6;
    const int lane = tid & 63;
    const int n0 = blockIdx.x * BN;
    const int m0 = blockIdx.y * BM;
    const int bb = blockIdx.z;

    const float* sc = (const float*)(wsb + WS_SCALES);
    const int srow = lane >> 2;
    const int lrow = lane & 15;
    const int quad = lane >> 4;
    const int wm = (wid % WGM) * (BM / WGM);         // 0 / 32
    const int wn = (wid / WGM) * (BN / WGM);         // 0 / 32
    // source-side chunk swizzle (rule #21): LDS dest linear, src chunk XOR'd
    const int xco = ((lane & 3) ^ ((lane >> 3) & 3)) << 4;
    const char* zp = wsb + WS_ZERO + xco;

    int4v acc3[FM][FN] = {};
    int4v accS[FM][FN] = {};

    auto src_ptr = [&](int s, int k0) -> const char* {
        const char* g;
        if (s < ISS_A) {
            int m = m0 + s * 16 + srow;
            if (MODE == 0)
                g = wsb + WS_W1Q + (size_t)m * 512 + k0 + xco;
            else if (MODE == 1)
                g = wsb + WS_W2Q + (size_t)m * 2304 + k0 + xco;
            else
                g = (k0 < 256) ? wsb + WS_W3Q + (size_t)m * 256 + k0 + xco
                               : wsb + WS_WSQ + (size_t)m * 512 + (k0 - 256) + xco;
        } else {
            int n = n0 + (s - ISS_A) * 16 + srow;
            g = zp;
            if (MODE == 0) {
                g = wsb + WS_A0 + (size_t)n * 512 + k0 + xco;
            } else if (MODE == 1) {
                unsigned b = (unsigned)n / 196u;
                unsigned hw = (unsigned)n - b * 196u;
                int oh = hw / 14, ow = hw - oh * 14;
                int tap = k0 >> 8;
                int kh = tap / 3, kw = tap - kh * 3;
                int c0 = k0 & 255;
                int ih = 2 * oh - 1 + kh, iw = 2 * ow - 1 + kw;
                if (ih >= 0 && ih < 28 && iw >= 0 && iw < 28)
                    g = wsb + WS_A1 + ((size_t)b * 784 + ih * 28 + iw) * 256 + c0 + xco;
            } else {
                if (n < 196) {
                    if (k0 < 256) {
                        g = wsb + WS_A2 + ((size_t)bb * 196 + n) * 256 + k0 + xco;
                    } else {
                        int oh = n / 14, ow = n - oh * 14;
                        int ps = oh * 56 + ow * 2;
                        g = wsb + WS_A0 + ((size_t)bb * 784 + ps) * 512 + (k0 - 256) + xco;
                    }
                }
            }
        }
        return g;
    };

    auto stage = [&](int t, char* buf) {
        const int k0 = t * 64;
#pragma unroll
        for (int ii = 0; ii < NI; ii++) {
            const int s = wid + ii * 4;
            gll16(src_ptr(s, k0), buf + s * 1024);   // lds dest wave-uniform, linear
        }
    };

    stage(0, lds);
    stage(1, lds + LDS_STAGE);                       // depth-2 prefetch
    for (int t = 0; t < NSTEP; ++t) {
        char* cur = lds + (t % 3) * LDS_STAGE;
        if (t == NSTEP - 1) {
            VMCNT_BAR(0);                            // final: drain own last tile
        } else {
            VMCNT_BAR(2);                            // tile t done; t+1's 2 in flight
        }
        if (t + 2 < NSTEP) stage(t + 2, lds + ((t + 2) % 3) * LDS_STAGE);

        int4v afr[FM], bfr[FN];
#pragma unroll
        for (int i = 0; i < FM; i++) {
            int m = wm + i * 16 + lrow;
            afr[i] = *(const int4v*)(cur + m * 64 + ((quad ^ ((m >> 1) & 3)) << 4));
        }
#pragma unroll
        for (int j = 0; j < FN; j++) {
            int n = wn + j * 16 + lrow;
            bfr[j] = *(const int4v*)(cur + (BM + n) * 64 + ((quad ^ ((n >> 1) & 3)) << 4));
        }
        if (MODE != 2 || t < 4) {
#pragma unroll
            for (int i = 0; i < FM; i++)
#pragma unroll
                for (int j = 0; j < FN; j++)
                    acc3[i][j] = __builtin_amdgcn_mfma_i32_16x16x64_i8(afr[i], bfr[j], acc3[i][j], 0, 0, 0);
        } else {
#pragma unroll
            for (int i = 0; i < FM; i++)
#pragma unroll
                for (int j = 0; j < FN; j++)
                    accS[i][j] = __builtin_amdgcn_mfma_i32_16x16x64_i8(afr[i], bfr[j], accS[i][j], 0, 0, 0);
        }
    }

    // ---------------- epilogue (C/D map: col=lane&15, row=quad*4+reg) ----------------
    if constexpr (MODE == 0 || MODE == 1) {
        const float alpha = sc[MODE] / 16129.0f;
        const float* bi = (const float*)(wsb + (MODE == 0 ? WS_BI1 : WS_BI2));
        signed char* outp = (signed char*)(wsb + (MODE == 0 ? WS_A1 : WS_A2));
        __syncthreads();   // all last-tile LDS reads done; reuse lds for epi
#pragma unroll
        for (int i = 0; i < FM; i++) {
            int mloc = wm + i * 16 + quad * 4;      // local m of r=0
            int mb = m0 + mloc;
            float bt[4];
#pragma unroll
            for (int r = 0; r < 4; r++) bt[r] = bi[mb + r] * (2.0f / 127.0f);
#pragma unroll
            for (int j = 0; j < FN; j++) {
                int nloc = wn + j * 16 + lrow;
                unsigned pk = 0;
#pragma unroll
                for (int r = 0; r < 4; r++) {
                    float v = alpha * (float)acc3[i][j][r] + bt[r];
                    int q = (int)rintf(127.0f * fminf(fmaxf(2.0f * v, 0.0f), 1.0f));
                    pk |= (unsigned)(q & 0xFF) << (8 * r);
                }
                *(unsigned*)(lds + nloc * BMP + mloc) = pk;
            }
        }
        __syncthreads();
        // coalesced copy-out: rows are [n][256] m-contig, 64 rows x 4 segs = 256
        {
            int row = tid >> 2, seg = tid & 3;
            uint4 v = *(const uint4*)(lds + row * BMP + seg * 16);
            *(uint4*)(outp + (size_t)(n0 + row) * 256 + m0 + seg * 16) = v;
        }
    } else {
        const float c2 = sc[1], c3 = sc[2], cS = sc[3];
        const float* bi3 = (const float*)(wsb + WS_BI3);
        const float* bis = (const float*)(wsb + WS_BIS);
        float* ldsF = (float*)lds;
        constexpr int LDN = BN + 4;                  // 68
        __syncthreads();   // last-tile LDS reads done before overwriting buffers
        // single pass: all 4 waves write their disjoint 32x32 quadrant
#pragma unroll
        for (int i = 0; i < FM; i++) {
            int mloc = wm + i * 16 + quad * 4;       // [0,64)
            int mg = m0 + mloc;
            float bt[4];
#pragma unroll
            for (int r = 0; r < 4; r++)
                bt[r] = bi3[mg + r] * (c3 / (127.0f * c2)) + bis[mg + r] * (1.0f / 127.0f);
#pragma unroll
            for (int j = 0; j < FN; j++) {
                int nloc = wn + j * 16 + lrow;
#pragma unroll
                for (int r = 0; r < 4; r++) {
                    float v = (c3 * (float)acc3[i][j][r] + cS * (float)accS[i][j][r])
                                  * (0.5f / 16129.0f) + bt[r];
                    v = v < 0.0f ? 0.0f : (v > 6.0f ? 6.0f : v);  // NaN-propagating
                    ldsF[(mloc + r) * LDN + nloc] = v;
                }
            }
        }
        __syncthreads();
        // copy out 64 rows x 64 floats: 256 threads, 1 row-seg (16 floats) each
        {
            int row = tid >> 2, seg = tid & 3;
            int nbase = n0 + seg * 16;
            const float* src = ldsF + row * LDN + seg * 16;
            float* dst = dout + ((size_t)bb * 1024 + m0 + row) * 196 + nbase;
            if (nbase + 16 <= 196) {
                *(f32x4*)(dst + 0)  = *(const f32x4*)(src + 0);
                *(f32x4*)(dst + 4)  = *(const f32x4*)(src + 4);
                *(f32x4*)(dst + 8)  = *(const f32x4*)(src + 8);
                *(f32x4*)(dst + 12) = *(const f32x4*)(src + 12);
            } else {
                for (int q = 0; q < 16 && nbase + q < 196; q++) dst[q] = src[q];
            }
        }
    }
}

extern "C" void kernel_launch(void* const* d_in, const int* in_sizes, int n_in,
                              void* d_out, int out_size, void* d_ws, size_t ws_size,
                              hipStream_t stream) {
    const float* x   = (const float*)d_in[0];
    const float* w1  = (const float*)d_in[1];
    const float* b1  = (const float*)d_in[2];
    const float* w2  = (const float*)d_in[3];
    const float* b2  = (const float*)d_in[4];
    const float* w3  = (const float*)d_in[5];
    const float* b3  = (const float*)d_in[6];
    const float* wsd = (const float*)d_in[7];
    const float* bs  = (const float*)d_in[8];
    float* out = (float*)d_out;
    char* wsb = (char*)d_ws;

    k_init<<<16, 256, 0, stream>>>((float*)wsb);
    k_maxabs<<<dim3(128, 4), 256, 0, stream>>>(w1, w2, w3, wsd, (float*)(wsb + WS_SCALES));
    k_quant_w<<<dim3(96, 8), 256, 0, stream>>>(w1, w2, w3, wsd, b1, b2, b3, bs, wsb);
    k_quant_x<<<dim3(7, 16, 64), 256, 0, stream>>>(x, (signed char*)(wsb + WS_A0));
    k_conv<0><<<dim3(784, 4, 1), 256, 0, stream>>>(wsb, out);   // conv1: 3136 blocks
    k_conv<1><<<dim3(196, 4, 1), 256, 0, stream>>>(wsb, out);   // conv2:  784 blocks
    k_conv<2><<<dim3(4, 16, 64), 256, 0, stream>>>(wsb, out);   // conv3: 4096 blocks
}